// Round 1
// baseline (382.284 us; speedup 1.0000x reference)
//
#include <hip/hip_runtime.h>
#include <cstdint>
#include <cstddef>

// GCN 2-layer: out = GCNConv(relu(GCNConv(x,W1,b1)), W2, b2)
// norm factorization: out[d] = dinv[d] * sum_{s->d} (dinv[s]*h[s])  (+ self loop s=d)
// Self-loops handled by initializing accumulator = dinv[i]*h[i] (GEMM epilogue writes both).

__global__ void deg_init_kernel(int* __restrict__ deg, int n) {
  int i = blockIdx.x * blockDim.x + threadIdx.x;
  if (i < n) deg[i] = 1;  // self-loop
}

__global__ void deg_count_kernel(const int* __restrict__ dst, int E, int* __restrict__ deg) {
  int e = blockIdx.x * blockDim.x + threadIdx.x;
  if (e < E) atomicAdd(&deg[dst[e]], 1);
}

__global__ void dinv_kernel(const int* __restrict__ deg, float* __restrict__ dinv, int n) {
  int i = blockIdx.x * blockDim.x + threadIdx.x;
  if (i < n) dinv[i] = 1.0f / sqrtf((float)deg[i]);  // deg >= 1 always
}

// h1s[i][c] = dinv[i] * sum_k x[i][k]*W1[k][c];  acc1 = copy of h1s (self-loop init)
__global__ __launch_bounds__(256) void gemm1_kernel(
    const float* __restrict__ x, const float* __restrict__ W1,
    const float* __restrict__ dinv, float* __restrict__ h1s,
    float* __restrict__ acc1, int N) {
  __shared__ float ws[128 * 64];   // 32 KB
  __shared__ float xs[32 * 128];   // 16 KB
  const int t = threadIdx.x;
  const int rowBase = blockIdx.x * 32;
  for (int i = t; i < 128 * 64; i += 256) ws[i] = W1[i];
  for (int i = t; i < 32 * 128; i += 256) {
    int r = i >> 7, k = i & 127;
    int row = rowBase + r;
    xs[i] = (row < N) ? x[(size_t)row * 128 + k] : 0.0f;
  }
  __syncthreads();
  const int c = t & 63;     // output column 0..63
  const int rg = t >> 6;    // row group 0..3, 8 rows each
  float acc[8];
#pragma unroll
  for (int r = 0; r < 8; ++r) acc[r] = 0.0f;
  const float* xrow = &xs[rg * 8 * 128];
  for (int k = 0; k < 128; ++k) {
    float wv = ws[k * 64 + c];  // 2-way bank alias across wave64 = free
#pragma unroll
    for (int r = 0; r < 8; ++r) acc[r] += xrow[r * 128 + k] * wv;  // xs broadcast
  }
#pragma unroll
  for (int r = 0; r < 8; ++r) {
    int row = rowBase + rg * 8 + r;
    if (row < N) {
      float v = acc[r] * dinv[row];
      h1s[(size_t)row * 64 + c] = v;
      acc1[(size_t)row * 64 + c] = v;
    }
  }
}

// one wave64 per edge: 64 features
__global__ void scatter64_kernel(const int* __restrict__ src, const int* __restrict__ dst,
                                 const float* __restrict__ h, float* __restrict__ acc, int E) {
  int gid = blockIdx.x * blockDim.x + threadIdx.x;
  int e = gid >> 6;
  int lane = gid & 63;
  if (e < E) {
    int s = src[e];
    int d = dst[e];
    float v = h[(size_t)s * 64 + lane];
    atomicAdd(&acc[(size_t)d * 64 + lane], v);
  }
}

// prologue: row = relu(dinv*acc1 + b1); h2s[i][c] = dinv[i]*(row @ W2); acc2 = copy
__global__ __launch_bounds__(256) void gemm2_kernel(
    const float* __restrict__ acc1, const float* __restrict__ W2,
    const float* __restrict__ b1, const float* __restrict__ dinv,
    float* __restrict__ h2s, float* __restrict__ acc2, int N) {
  __shared__ float ws[64 * 32];   // 8 KB
  __shared__ float xs[32 * 64];   // 8 KB
  const int t = threadIdx.x;
  const int rowBase = blockIdx.x * 32;
  for (int i = t; i < 64 * 32; i += 256) ws[i] = W2[i];
  for (int i = t; i < 32 * 64; i += 256) {
    int r = i >> 6, k = i & 63;
    int row = rowBase + r;
    float v = 0.0f;
    if (row < N) {
      v = dinv[row] * acc1[(size_t)row * 64 + k] + b1[k];
      v = fmaxf(v, 0.0f);  // relu
    }
    xs[i] = v;
  }
  __syncthreads();
  const int c = t & 31;   // output column 0..31
  const int rg = t >> 5;  // row group 0..7, 4 rows each
  float acc[4] = {0.0f, 0.0f, 0.0f, 0.0f};
  const float* xrow = &xs[rg * 4 * 64];
  for (int k = 0; k < 64; ++k) {
    float wv = ws[k * 32 + c];
#pragma unroll
    for (int r = 0; r < 4; ++r) acc[r] += xrow[r * 64 + k] * wv;
  }
#pragma unroll
  for (int r = 0; r < 4; ++r) {
    int row = rowBase + rg * 4 + r;
    if (row < N) {
      float v = acc[r] * dinv[row];
      h2s[(size_t)row * 32 + c] = v;
      acc2[(size_t)row * 32 + c] = v;
    }
  }
}

// half-wave (32 lanes) per edge: 32 features
__global__ void scatter32_kernel(const int* __restrict__ src, const int* __restrict__ dst,
                                 const float* __restrict__ h, float* __restrict__ acc, int E) {
  int gid = blockIdx.x * blockDim.x + threadIdx.x;
  int e = gid >> 5;
  int lane = gid & 31;
  if (e < E) {
    int s = src[e];
    int d = dst[e];
    float v = h[(size_t)s * 32 + lane];
    atomicAdd(&acc[(size_t)d * 32 + lane], v);
  }
}

__global__ void finalize_kernel(float* __restrict__ out, const float* __restrict__ dinv,
                                const float* __restrict__ b2, int total) {
  int i = blockIdx.x * blockDim.x + threadIdx.x;
  if (i < total) {
    int row = i >> 5;
    int c = i & 31;
    out[i] = dinv[row] * out[i] + b2[c];
  }
}

extern "C" void kernel_launch(void* const* d_in, const int* in_sizes, int n_in,
                              void* d_out, int out_size, void* d_ws, size_t ws_size,
                              hipStream_t stream) {
  const float* x = (const float*)d_in[0];
  const int* edge_index = (const int*)d_in[1];
  // d_in[2] = edge_attr (unused by reference)
  const float* W1 = (const float*)d_in[3];
  const float* b1 = (const float*)d_in[4];
  const float* W2 = (const float*)d_in[5];
  const float* b2 = (const float*)d_in[6];
  float* out = (float*)d_out;

  const int N = in_sizes[0] / 128;  // 50000
  const int E = in_sizes[1] / 2;    // 800000
  const int* src = edge_index;
  const int* dst = edge_index + E;

  char* ws = (char*)d_ws;
  size_t off = 0;
  auto alloc = [&](size_t bytes) -> void* {
    void* p = ws + off;
    off += (bytes + 255) & ~(size_t)255;
    return p;
  };
  int* deg = (int*)alloc((size_t)N * 4);
  float* dinv = (float*)alloc((size_t)N * 4);
  float* h1s = (float*)alloc((size_t)N * 64 * 4);   // dinv-scaled layer-1 hidden
  float* acc1 = (float*)alloc((size_t)N * 64 * 4);  // layer-1 accumulator
  float* h2s = (float*)alloc((size_t)N * 32 * 4);   // dinv-scaled layer-2 hidden
  // layer-2 accumulator lives directly in d_out (fully rewritten each call)

  deg_init_kernel<<<(N + 255) / 256, 256, 0, stream>>>(deg, N);
  deg_count_kernel<<<(E + 255) / 256, 256, 0, stream>>>(dst, E, deg);
  dinv_kernel<<<(N + 255) / 256, 256, 0, stream>>>(deg, dinv, N);
  gemm1_kernel<<<(N + 31) / 32, 256, 0, stream>>>(x, W1, dinv, h1s, acc1, N);
  scatter64_kernel<<<(E * 64 + 255) / 256, 256, 0, stream>>>(src, dst, h1s, acc1, E);
  gemm2_kernel<<<(N + 31) / 32, 256, 0, stream>>>(acc1, W2, b1, dinv, h2s, out, N);
  scatter32_kernel<<<(E * 32 + 255) / 256, 256, 0, stream>>>(src, dst, h2s, out, E);
  finalize_kernel<<<(N * 32 + 255) / 256, 256, 0, stream>>>(out, dinv, b2, N * 32);
}

// Round 2
// 241.414 us; speedup vs baseline: 1.5835x; 1.5835x over previous
//
#include <hip/hip_runtime.h>
#include <cstdint>
#include <cstddef>

// 2-layer GCN. norm factorization: out[d] = dinv[d]*(h_s[d] + sum_{s->d} h_s[s]),
// h_s[i] = dinv[i]*(x@W)[i]. Self-loop folded in as the h_s[d] term.
// Edge aggregation via device-built CSR (dst-bucketed) + per-node gather
// (NO global atomics on the feature accumulation -> no 200MB HBM write-through).

// ---------- degree / dinv ----------
__global__ void deg_init_kernel(int* __restrict__ deg, int n) {
  int i = blockIdx.x * blockDim.x + threadIdx.x;
  if (i < n) deg[i] = 1;  // self-loop
}

__global__ void deg_count_kernel(const int* __restrict__ dst, int E, int* __restrict__ deg) {
  int e = blockIdx.x * blockDim.x + threadIdx.x;
  if (e < E) atomicAdd(&deg[dst[e]], 1);
}

__global__ void dinv_kernel(const int* __restrict__ deg, float* __restrict__ dinv, int n) {
  int i = blockIdx.x * blockDim.x + threadIdx.x;
  if (i < n) dinv[i] = 1.0f / sqrtf((float)deg[i]);  // deg >= 1 always
}

// ---------- CSR build: exclusive scan of (deg-1) over N, then bucket fill ----------
__global__ __launch_bounds__(1024) void scan1_kernel(const int* __restrict__ deg,
                                                     int* __restrict__ offs,
                                                     int* __restrict__ bsum, int n) {
  int t = threadIdx.x;
  int gid = blockIdx.x * 1024 + t;
  int v = (gid < n) ? (deg[gid] - 1) : 0;  // edge-only in-degree
  int lane = t & 63, wid = t >> 6;
  int x = v;
#pragma unroll
  for (int off = 1; off < 64; off <<= 1) {
    int y = __shfl_up(x, off, 64);
    if (lane >= off) x += y;
  }
  __shared__ int wsum[16];
  if (lane == 63) wsum[wid] = x;
  __syncthreads();
  if (wid == 0) {
    int s = (lane < 16) ? wsum[lane] : 0;
#pragma unroll
    for (int off = 1; off < 16; off <<= 1) {
      int y = __shfl_up(s, off, 64);
      if (lane >= off) s += y;
    }
    if (lane < 16) wsum[lane] = s;
  }
  __syncthreads();
  int base = (wid > 0) ? wsum[wid - 1] : 0;
  int incl = base + x;
  if (gid < n) offs[gid] = incl - v;  // block-local exclusive
  if (t == 1023) bsum[blockIdx.x] = incl;
}

__global__ void scan2_kernel(int* __restrict__ bsum, int nb) {
  int lane = threadIdx.x;  // single wave, nb <= 64
  int v = (lane < nb) ? bsum[lane] : 0;
  int x = v;
#pragma unroll
  for (int off = 1; off < 64; off <<= 1) {
    int y = __shfl_up(x, off, 64);
    if (lane >= off) x += y;
  }
  if (lane < nb) bsum[lane] = x - v;  // exclusive base per block
}

__global__ __launch_bounds__(1024) void scan3_kernel(int* __restrict__ offs,
                                                     const int* __restrict__ bsum,
                                                     int* __restrict__ cursor, int n) {
  int gid = blockIdx.x * 1024 + threadIdx.x;
  if (gid < n) {
    int o = offs[gid] + bsum[blockIdx.x];
    offs[gid] = o;
    cursor[gid] = o;
  }
}

__global__ void fill_kernel(const int* __restrict__ src, const int* __restrict__ dst,
                            int* __restrict__ cursor, int* __restrict__ csr, int E) {
  int e = blockIdx.x * blockDim.x + threadIdx.x;
  if (e < E) {
    int d = dst[e];
    int p = atomicAdd(&cursor[d], 1);  // after this, cursor[d] = row end
    csr[p] = src[e];
  }
}

// ---------- GEMM1: h1s[i][c] = dinv[i] * (x @ W1)[i][c]   (N x 128 @ 128 x 64) ----------
// 64 rows/block, 256 threads, 4x4 register tile, quad-swizzled LDS (conflict-free b128).
__global__ __launch_bounds__(256) void gemm1_kernel(
    const float* __restrict__ x, const float* __restrict__ W1,
    const float* __restrict__ dinv, float* __restrict__ h1s, int N) {
  __shared__ float ws[128 * 64];  // 32 KB, [k][c]
  __shared__ float xs[64 * 128];  // 32 KB, [r][k] quad-swizzled: quad kq stored at kq^((r>>2)&7)
  const int t = threadIdx.x;
  const int rowBase = blockIdx.x * 64;
  float4* ws4 = (float4*)ws;
  float4* xs4 = (float4*)xs;
  for (int i = t; i < 128 * 16; i += 256) ws4[i] = ((const float4*)W1)[i];
  for (int i = t; i < 64 * 32; i += 256) {
    int r = i >> 5, kq = i & 31;
    int row = rowBase + r;
    float4 v = make_float4(0.f, 0.f, 0.f, 0.f);
    if (row < N) v = ((const float4*)x)[(size_t)row * 32 + kq];
    xs4[r * 32 + (kq ^ ((r >> 2) & 7))] = v;
  }
  __syncthreads();
  const int g = t & 15;   // col group: c0 = 4g (64 cols)
  const int rg = t >> 4;  // row group: r0 = 4rg (64 rows)
  const int swz = rg & 7;
  float acc[4][4] = {};
  for (int kq = 0; kq < 32; ++kq) {
    float4 a[4];
#pragma unroll
    for (int j = 0; j < 4; ++j) a[j] = xs4[(4 * rg + j) * 32 + (kq ^ swz)];
    float4 w[4];
#pragma unroll
    for (int kk = 0; kk < 4; ++kk) w[kk] = ws4[(4 * kq + kk) * 16 + g];
#pragma unroll
    for (int j = 0; j < 4; ++j) {
      acc[j][0] += a[j].x * w[0].x + a[j].y * w[1].x + a[j].z * w[2].x + a[j].w * w[3].x;
      acc[j][1] += a[j].x * w[0].y + a[j].y * w[1].y + a[j].z * w[2].y + a[j].w * w[3].y;
      acc[j][2] += a[j].x * w[0].z + a[j].y * w[1].z + a[j].z * w[2].z + a[j].w * w[3].z;
      acc[j][3] += a[j].x * w[0].w + a[j].y * w[1].w + a[j].z * w[2].w + a[j].w * w[3].w;
    }
  }
#pragma unroll
  for (int j = 0; j < 4; ++j) {
    int row = rowBase + 4 * rg + j;
    if (row < N) {
      float dv = dinv[row];
      float4 o = make_float4(acc[j][0] * dv, acc[j][1] * dv, acc[j][2] * dv, acc[j][3] * dv);
      ((float4*)h1s)[(size_t)row * 16 + g] = o;
    }
  }
}

// ---------- gather layer 1: a1[d] = relu(dinv[d]*(h1s[d] + sum_in h1s[s]) + b1) ----------
__global__ void gather64_kernel(const float* __restrict__ h1s, const int* __restrict__ csr,
                                const int* __restrict__ offs, const int* __restrict__ cursor,
                                const float* __restrict__ dinv, const float* __restrict__ b1,
                                float* __restrict__ a1, int N) {
  int t = threadIdx.x;
  int d = blockIdx.x * 4 + (t >> 6);  // one wave per node
  if (d >= N) return;
  int lane = t & 63;
  int beg = offs[d], end = cursor[d];
  float acc = h1s[(size_t)d * 64 + lane];  // self-loop
  float acc2 = 0.f;
  int j = beg;
  for (; j + 1 < end; j += 2) {
    int s0 = csr[j], s1 = csr[j + 1];
    acc += h1s[(size_t)s0 * 64 + lane];
    acc2 += h1s[(size_t)s1 * 64 + lane];
  }
  if (j < end) acc += h1s[(size_t)csr[j] * 64 + lane];
  acc += acc2;
  a1[(size_t)d * 64 + lane] = fmaxf(acc * dinv[d] + b1[lane], 0.f);
}

// ---------- GEMM2: h2s[i][c] = dinv[i] * (a1 @ W2)[i][c]   (N x 64 @ 64 x 32) ----------
__global__ __launch_bounds__(256) void gemm2_kernel(
    const float* __restrict__ a1, const float* __restrict__ W2,
    const float* __restrict__ dinv, float* __restrict__ h2s, int N) {
  __shared__ float ws[64 * 32];   // 8 KB, [k][c]
  __shared__ float xs[128 * 64];  // 32 KB, [r][k] quad-swizzled
  const int t = threadIdx.x;
  const int rowBase = blockIdx.x * 128;
  float4* ws4 = (float4*)ws;
  float4* xs4 = (float4*)xs;
  for (int i = t; i < 64 * 8; i += 256) ws4[i] = ((const float4*)W2)[i];
  for (int i = t; i < 128 * 16; i += 256) {
    int r = i >> 4, kq = i & 15;
    int row = rowBase + r;
    float4 v = make_float4(0.f, 0.f, 0.f, 0.f);
    if (row < N) v = ((const float4*)a1)[(size_t)row * 16 + kq];
    xs4[r * 16 + (kq ^ ((r >> 2) & 7))] = v;
  }
  __syncthreads();
  const int g = t & 7;   // col group: c0 = 4g (32 cols)
  const int rg = t >> 3; // row group: r0 = 4rg (128 rows)
  const int swz = rg & 7;
  float acc[4][4] = {};
  for (int kq = 0; kq < 16; ++kq) {
    float4 a[4];
#pragma unroll
    for (int j = 0; j < 4; ++j) a[j] = xs4[(4 * rg + j) * 16 + (kq ^ swz)];
    float4 w[4];
#pragma unroll
    for (int kk = 0; kk < 4; ++kk) w[kk] = ws4[(4 * kq + kk) * 8 + g];
#pragma unroll
    for (int j = 0; j < 4; ++j) {
      acc[j][0] += a[j].x * w[0].x + a[j].y * w[1].x + a[j].z * w[2].x + a[j].w * w[3].x;
      acc[j][1] += a[j].x * w[0].y + a[j].y * w[1].y + a[j].z * w[2].y + a[j].w * w[3].y;
      acc[j][2] += a[j].x * w[0].z + a[j].y * w[1].z + a[j].z * w[2].z + a[j].w * w[3].z;
      acc[j][3] += a[j].x * w[0].w + a[j].y * w[1].w + a[j].z * w[2].w + a[j].w * w[3].w;
    }
  }
#pragma unroll
  for (int j = 0; j < 4; ++j) {
    int row = rowBase + 4 * rg + j;
    if (row < N) {
      float dv = dinv[row];
      float4 o = make_float4(acc[j][0] * dv, acc[j][1] * dv, acc[j][2] * dv, acc[j][3] * dv);
      ((float4*)h2s)[(size_t)row * 8 + g] = o;
    }
  }
}

// ---------- gather layer 2: out[d] = dinv[d]*(h2s[d] + sum_in h2s[s]) + b2 ----------
// one wave per node; lanes 0-31 even edges, 32-63 odd edges, combine via shfl_xor(32).
__global__ void gather32_kernel(const float* __restrict__ h2s, const int* __restrict__ csr,
                                const int* __restrict__ offs, const int* __restrict__ cursor,
                                const float* __restrict__ dinv, const float* __restrict__ b2,
                                float* __restrict__ out, int N) {
  int t = threadIdx.x;
  int d = blockIdx.x * 4 + (t >> 6);
  if (d >= N) return;
  int lane = t & 63;
  int f = lane & 31;
  int half = lane >> 5;
  int beg = offs[d], end = cursor[d];
  float acc = (half == 0) ? h2s[(size_t)d * 32 + f] : 0.f;  // self-loop in half 0
  for (int j = beg + half; j < end; j += 2)
    acc += h2s[(size_t)csr[j] * 32 + f];
  acc += __shfl_xor(acc, 32, 64);
  if (half == 0) out[(size_t)d * 32 + f] = acc * dinv[d] + b2[f];
}

extern "C" void kernel_launch(void* const* d_in, const int* in_sizes, int n_in,
                              void* d_out, int out_size, void* d_ws, size_t ws_size,
                              hipStream_t stream) {
  const float* x = (const float*)d_in[0];
  const int* edge_index = (const int*)d_in[1];
  // d_in[2] = edge_attr (unused by reference)
  const float* W1 = (const float*)d_in[3];
  const float* b1 = (const float*)d_in[4];
  const float* W2 = (const float*)d_in[5];
  const float* b2 = (const float*)d_in[6];
  float* out = (float*)d_out;

  const int N = in_sizes[0] / 128;  // 50000
  const int E = in_sizes[1] / 2;    // 800000
  const int* src = edge_index;
  const int* dst = edge_index + E;

  char* ws = (char*)d_ws;
  size_t off = 0;
  auto alloc = [&](size_t bytes) -> void* {
    void* p = ws + off;
    off += (bytes + 255) & ~(size_t)255;
    return p;
  };
  int* deg = (int*)alloc((size_t)N * 4);
  float* dinv = (float*)alloc((size_t)N * 4);
  int* offs = (int*)alloc((size_t)N * 4);
  int* cursor = (int*)alloc((size_t)N * 4);
  int* bsum = (int*)alloc(64 * 4);
  int* csr = (int*)alloc((size_t)E * 4);
  float* h1s = (float*)alloc((size_t)N * 64 * 4);  // layer-1 scaled hidden (reused as h2s)
  float* a1 = (float*)alloc((size_t)N * 64 * 4);   // layer-1 activations (post relu)
  float* h2s = h1s;                                // alias: h1s dead after gather64

  const int nb = (N + 1023) / 1024;  // 49 (<= 64)

  deg_init_kernel<<<(N + 255) / 256, 256, 0, stream>>>(deg, N);
  deg_count_kernel<<<(E + 255) / 256, 256, 0, stream>>>(dst, E, deg);
  dinv_kernel<<<(N + 255) / 256, 256, 0, stream>>>(deg, dinv, N);
  scan1_kernel<<<nb, 1024, 0, stream>>>(deg, offs, bsum, N);
  scan2_kernel<<<1, 64, 0, stream>>>(bsum, nb);
  scan3_kernel<<<nb, 1024, 0, stream>>>(offs, bsum, cursor, N);
  fill_kernel<<<(E + 255) / 256, 256, 0, stream>>>(src, dst, cursor, csr, E);
  gemm1_kernel<<<(N + 63) / 64, 256, 0, stream>>>(x, W1, dinv, h1s, N);
  gather64_kernel<<<(N + 3) / 4, 256, 0, stream>>>(h1s, csr, offs, cursor, dinv, b1, a1, N);
  gemm2_kernel<<<(N + 127) / 128, 256, 0, stream>>>(a1, W2, dinv, h2s, N);
  gather32_kernel<<<(N + 3) / 4, 256, 0, stream>>>(h2s, csr, offs, cursor, dinv, b2, out, N);
}

// Round 3
// 127.967 us; speedup vs baseline: 2.9874x; 1.8865x over previous
//
#include <hip/hip_runtime.h>
#include <cstdint>
#include <cstddef>

// 2-layer GCN. norm factorization: out[d] = dinv[d]*(h_s[d] + sum_{s->d} h_s[s]),
// h_s[i] = dinv[i]*(x@W)[i]. Self-loop folded in as the h_s[d] term.
// Edge aggregation: deterministic 2-level counting sort -> CSR -> per-node gather.
// No global atomics anywhere on the feature path; sort writes are (mostly) coalesced.

#define SHIFT 7                 // 128 nodes per coarse bucket
#define NPB 128
#define CHUNK 4096              // edges per histogram/scatter block
#define IMG_CAP 8192            // LDS csr-image capacity (4x expected bucket load)

// ---- K1: per-block bucket histogram. hist[b*nWG + w] = count of bucket b in block w ----
__global__ __launch_bounds__(256) void hist_kernel(const int* __restrict__ dst, int E, int nWG,
                                                   int B, int* __restrict__ hist) {
  __shared__ int h[512];
  int t = threadIdx.x, w = blockIdx.x;
  for (int i = t; i < B; i += 256) h[i] = 0;
  __syncthreads();
  int beg = w * CHUNK, end = min(beg + CHUNK, E);
  for (int i = beg + t; i < end; i += 256) atomicAdd(&h[dst[i] >> SHIFT], 1);
  __syncthreads();
  for (int i = t; i < B; i += 256) hist[i * nWG + w] = h[i];
}

// ---- K2a: exclusive scan of each bucket row (over blocks); also row total ----
__global__ __launch_bounds__(256) void rowscan_kernel(const int* __restrict__ hist, int nWG,
                                                      int* __restrict__ rowscan, int* __restrict__ total) {
  int b = blockIdx.x, t = threadIdx.x;  // nWG <= 256
  int v = (t < nWG) ? hist[b * nWG + t] : 0;
  int lane = t & 63, wid = t >> 6;
  int x = v;
#pragma unroll
  for (int o = 1; o < 64; o <<= 1) { int y = __shfl_up(x, o, 64); if (lane >= o) x += y; }
  __shared__ int wsum[4];
  if (lane == 63) wsum[wid] = x;
  __syncthreads();
  int bw = 0;
  for (int i = 0; i < wid; ++i) bw += wsum[i];
  int incl = bw + x;
  if (t < nWG) rowscan[b * nWG + t] = incl - v;
  if (t == nWG - 1) total[b] = incl;
}

// ---- K2b: exclusive scan of bucket totals -> base[b]; base[B] = E ----
__global__ __launch_bounds__(512) void basescan_kernel(const int* __restrict__ total, int B,
                                                       int* __restrict__ base) {
  int t = threadIdx.x;  // B < 512
  int v = (t < B) ? total[t] : 0;
  int lane = t & 63, wid = t >> 6;
  int x = v;
#pragma unroll
  for (int o = 1; o < 64; o <<= 1) { int y = __shfl_up(x, o, 64); if (lane >= o) x += y; }
  __shared__ int wsum[8];
  if (lane == 63) wsum[wid] = x;
  __syncthreads();
  int bw = 0;
  for (int i = 0; i < wid; ++i) bw += wsum[i];
  int excl = bw + x - v;
  if (t <= B) base[t] = excl;
}

// ---- K3: scatter packed keys (local<<16 | src) into bucket-contiguous layout ----
__global__ __launch_bounds__(256) void scatterkeys_kernel(const int* __restrict__ src,
                                                          const int* __restrict__ dst, int E, int nWG,
                                                          int B, const int* __restrict__ rowscan,
                                                          const int* __restrict__ base,
                                                          unsigned* __restrict__ keys) {
  __shared__ int cur[512];
  int t = threadIdx.x, w = blockIdx.x;
  for (int i = t; i < B; i += 256) cur[i] = base[i] + rowscan[i * nWG + w];
  __syncthreads();
  int beg = w * CHUNK, end = min(beg + CHUNK, E);
  for (int i = beg + t; i < end; i += 256) {
    int d = dst[i], s = src[i];
    int b = d >> SHIFT;
    int p = atomicAdd(&cur[b], 1);
    keys[p] = ((unsigned)(d & (NPB - 1)) << 16) | (unsigned)s;  // requires N <= 65536
  }
}

// ---- K4: per-bucket: per-node counts -> eoff/ecnt/dinv; sort keys -> csr (LDS image) ----
__global__ __launch_bounds__(256) void bucket_build_kernel(const unsigned* __restrict__ keys,
                                                           const int* __restrict__ base, int N,
                                                           int* __restrict__ csr, int* __restrict__ eoff,
                                                           int* __restrict__ ecnt, float* __restrict__ dinv) {
  __shared__ int cnt[NPB], loffs[NPB], cur[NPB];
  __shared__ int image[IMG_CAP];
  int b = blockIdx.x, t = threadIdx.x;
  int nb = b << SHIFT;
  int nn = min(NPB, N - nb);
  int gbeg = base[b], gend = base[b + 1];
  int m = gend - gbeg;
  if (t < NPB) cnt[t] = 0;
  __syncthreads();
  for (int i = gbeg + t; i < gend; i += 256) atomicAdd(&cnt[keys[i] >> 16], 1);
  __syncthreads();
  if (t < 64) {  // pair-wise exclusive scan of cnt[0..127] in one wave
    int v0 = cnt[2 * t], v1 = cnt[2 * t + 1];
    int s = v0 + v1, x = s;
#pragma unroll
    for (int o = 1; o < 64; o <<= 1) { int y = __shfl_up(x, o, 64); if (t >= o) x += y; }
    int e = x - s;
    loffs[2 * t] = e;      cur[2 * t] = e;
    loffs[2 * t + 1] = e + v0;  cur[2 * t + 1] = e + v0;
  }
  __syncthreads();
  for (int n = t; n < nn; n += 256) {
    eoff[nb + n] = gbeg + loffs[n];
    ecnt[nb + n] = cnt[n];
    dinv[nb + n] = 1.0f / sqrtf((float)(cnt[n] + 1));  // +1 self-loop
  }
  if (m <= IMG_CAP) {
    for (int i = gbeg + t; i < gend; i += 256) {
      unsigned k = keys[i];
      int p = atomicAdd(&cur[k >> 16], 1);
      image[p] = (int)(k & 0xFFFFu);
    }
    __syncthreads();
    for (int i = t; i < m; i += 256) csr[gbeg + i] = image[i];
  } else {  // statistically unreachable fallback
    for (int i = gbeg + t; i < gend; i += 256) {
      unsigned k = keys[i];
      int p = atomicAdd(&cur[k >> 16], 1);
      csr[gbeg + p] = (int)(k & 0xFFFFu);
    }
  }
}

// ---- GEMM1: h1s[i][c] = dinv[i] * (x @ W1)[i][c]   (N x 128 @ 128 x 64) ----
__global__ __launch_bounds__(256) void gemm1_kernel(
    const float* __restrict__ x, const float* __restrict__ W1,
    const float* __restrict__ dinv, float* __restrict__ h1s, int N) {
  __shared__ float ws[128 * 64];
  __shared__ float xs[64 * 128];
  const int t = threadIdx.x;
  const int rowBase = blockIdx.x * 64;
  float4* ws4 = (float4*)ws;
  float4* xs4 = (float4*)xs;
  for (int i = t; i < 128 * 16; i += 256) ws4[i] = ((const float4*)W1)[i];
  for (int i = t; i < 64 * 32; i += 256) {
    int r = i >> 5, kq = i & 31;
    int row = rowBase + r;
    float4 v = make_float4(0.f, 0.f, 0.f, 0.f);
    if (row < N) v = ((const float4*)x)[(size_t)row * 32 + kq];
    xs4[r * 32 + (kq ^ ((r >> 2) & 7))] = v;
  }
  __syncthreads();
  const int g = t & 15;
  const int rg = t >> 4;
  const int swz = rg & 7;
  float acc[4][4] = {};
  for (int kq = 0; kq < 32; ++kq) {
    float4 a[4];
#pragma unroll
    for (int j = 0; j < 4; ++j) a[j] = xs4[(4 * rg + j) * 32 + (kq ^ swz)];
    float4 w[4];
#pragma unroll
    for (int kk = 0; kk < 4; ++kk) w[kk] = ws4[(4 * kq + kk) * 16 + g];
#pragma unroll
    for (int j = 0; j < 4; ++j) {
      acc[j][0] += a[j].x * w[0].x + a[j].y * w[1].x + a[j].z * w[2].x + a[j].w * w[3].x;
      acc[j][1] += a[j].x * w[0].y + a[j].y * w[1].y + a[j].z * w[2].y + a[j].w * w[3].y;
      acc[j][2] += a[j].x * w[0].z + a[j].y * w[1].z + a[j].z * w[2].z + a[j].w * w[3].z;
      acc[j][3] += a[j].x * w[0].w + a[j].y * w[1].w + a[j].z * w[2].w + a[j].w * w[3].w;
    }
  }
#pragma unroll
  for (int j = 0; j < 4; ++j) {
    int row = rowBase + 4 * rg + j;
    if (row < N) {
      float dv = dinv[row];
      float4 o = make_float4(acc[j][0] * dv, acc[j][1] * dv, acc[j][2] * dv, acc[j][3] * dv);
      ((float4*)h1s)[(size_t)row * 16 + g] = o;
    }
  }
}

// ---- gather layer 1 (64 feats, 1 wave/node, 8-wide ILP) ----
__global__ __launch_bounds__(256) void gather64_kernel(
    const float* __restrict__ h1s, const int* __restrict__ csr, const int* __restrict__ eoff,
    const int* __restrict__ ecnt, const float* __restrict__ dinv, const float* __restrict__ b1,
    float* __restrict__ a1, int N) {
  int t = threadIdx.x;
  int d = blockIdx.x * 4 + (t >> 6);
  if (d >= N) return;
  int lane = t & 63;
  int beg = eoff[d], m = ecnt[d];
  float a0 = h1s[(size_t)d * 64 + lane], aA = 0.f, aB = 0.f, aC = 0.f;
  int j = 0;
  for (; j + 8 <= m; j += 8) {
    int s0 = csr[beg + j + 0], s1 = csr[beg + j + 1], s2 = csr[beg + j + 2], s3 = csr[beg + j + 3];
    int s4 = csr[beg + j + 4], s5 = csr[beg + j + 5], s6 = csr[beg + j + 6], s7 = csr[beg + j + 7];
    float v0 = h1s[(size_t)s0 * 64 + lane], v1 = h1s[(size_t)s1 * 64 + lane];
    float v2 = h1s[(size_t)s2 * 64 + lane], v3 = h1s[(size_t)s3 * 64 + lane];
    float v4 = h1s[(size_t)s4 * 64 + lane], v5 = h1s[(size_t)s5 * 64 + lane];
    float v6 = h1s[(size_t)s6 * 64 + lane], v7 = h1s[(size_t)s7 * 64 + lane];
    a0 += v0; aA += v1; aB += v2; aC += v3;
    a0 += v4; aA += v5; aB += v6; aC += v7;
  }
  for (; j + 4 <= m; j += 4) {
    int s0 = csr[beg + j + 0], s1 = csr[beg + j + 1], s2 = csr[beg + j + 2], s3 = csr[beg + j + 3];
    float v0 = h1s[(size_t)s0 * 64 + lane], v1 = h1s[(size_t)s1 * 64 + lane];
    float v2 = h1s[(size_t)s2 * 64 + lane], v3 = h1s[(size_t)s3 * 64 + lane];
    a0 += v0; aA += v1; aB += v2; aC += v3;
  }
  for (; j < m; ++j) a0 += h1s[(size_t)csr[beg + j] * 64 + lane];
  float acc = (a0 + aA) + (aB + aC);
  a1[(size_t)d * 64 + lane] = fmaxf(acc * dinv[d] + b1[lane], 0.f);
}

// ---- GEMM2: h2s[i][c] = dinv[i] * (a1 @ W2)[i][c]   (N x 64 @ 64 x 32) ----
__global__ __launch_bounds__(256) void gemm2_kernel(
    const float* __restrict__ a1, const float* __restrict__ W2,
    const float* __restrict__ dinv, float* __restrict__ h2s, int N) {
  __shared__ float ws[64 * 32];
  __shared__ float xs[128 * 64];
  const int t = threadIdx.x;
  const int rowBase = blockIdx.x * 128;
  float4* ws4 = (float4*)ws;
  float4* xs4 = (float4*)xs;
  for (int i = t; i < 64 * 8; i += 256) ws4[i] = ((const float4*)W2)[i];
  for (int i = t; i < 128 * 16; i += 256) {
    int r = i >> 4, kq = i & 15;
    int row = rowBase + r;
    float4 v = make_float4(0.f, 0.f, 0.f, 0.f);
    if (row < N) v = ((const float4*)a1)[(size_t)row * 16 + kq];
    xs4[r * 16 + (kq ^ ((r >> 2) & 7))] = v;
  }
  __syncthreads();
  const int g = t & 7;
  const int rg = t >> 3;
  const int swz = rg & 7;
  float acc[4][4] = {};
  for (int kq = 0; kq < 16; ++kq) {
    float4 a[4];
#pragma unroll
    for (int j = 0; j < 4; ++j) a[j] = xs4[(4 * rg + j) * 16 + (kq ^ swz)];
    float4 w[4];
#pragma unroll
    for (int kk = 0; kk < 4; ++kk) w[kk] = ws4[(4 * kq + kk) * 8 + g];
#pragma unroll
    for (int j = 0; j < 4; ++j) {
      acc[j][0] += a[j].x * w[0].x + a[j].y * w[1].x + a[j].z * w[2].x + a[j].w * w[3].x;
      acc[j][1] += a[j].x * w[0].y + a[j].y * w[1].y + a[j].z * w[2].y + a[j].w * w[3].y;
      acc[j][2] += a[j].x * w[0].z + a[j].y * w[1].z + a[j].z * w[2].z + a[j].w * w[3].z;
      acc[j][3] += a[j].x * w[0].w + a[j].y * w[1].w + a[j].z * w[2].w + a[j].w * w[3].w;
    }
  }
#pragma unroll
  for (int j = 0; j < 4; ++j) {
    int row = rowBase + 4 * rg + j;
    if (row < N) {
      float dv = dinv[row];
      float4 o = make_float4(acc[j][0] * dv, acc[j][1] * dv, acc[j][2] * dv, acc[j][3] * dv);
      ((float4*)h2s)[(size_t)row * 8 + g] = o;
    }
  }
}

// ---- gather layer 2 (32 feats, 2 nodes/wave, 4-wide ILP) ----
__global__ __launch_bounds__(256) void gather32_kernel(
    const float* __restrict__ h2s, const int* __restrict__ csr, const int* __restrict__ eoff,
    const int* __restrict__ ecnt, const float* __restrict__ dinv, const float* __restrict__ b2,
    float* __restrict__ out, int N) {
  int t = threadIdx.x;
  int d = blockIdx.x * 8 + (t >> 5);
  if (d >= N) return;
  int f = t & 31;
  int beg = eoff[d], m = ecnt[d];
  float a0 = h2s[(size_t)d * 32 + f], aA = 0.f, aB = 0.f, aC = 0.f;
  int j = 0;
  for (; j + 4 <= m; j += 4) {
    int s0 = csr[beg + j + 0], s1 = csr[beg + j + 1], s2 = csr[beg + j + 2], s3 = csr[beg + j + 3];
    float v0 = h2s[(size_t)s0 * 32 + f], v1 = h2s[(size_t)s1 * 32 + f];
    float v2 = h2s[(size_t)s2 * 32 + f], v3 = h2s[(size_t)s3 * 32 + f];
    a0 += v0; aA += v1; aB += v2; aC += v3;
  }
  for (; j < m; ++j) a0 += h2s[(size_t)csr[beg + j] * 32 + f];
  out[(size_t)d * 32 + f] = ((a0 + aA) + (aB + aC)) * dinv[d] + b2[f];
}

extern "C" void kernel_launch(void* const* d_in, const int* in_sizes, int n_in,
                              void* d_out, int out_size, void* d_ws, size_t ws_size,
                              hipStream_t stream) {
  const float* x = (const float*)d_in[0];
  const int* edge_index = (const int*)d_in[1];
  // d_in[2] = edge_attr (unused by reference)
  const float* W1 = (const float*)d_in[3];
  const float* b1 = (const float*)d_in[4];
  const float* W2 = (const float*)d_in[5];
  const float* b2 = (const float*)d_in[6];
  float* out = (float*)d_out;

  const int N = in_sizes[0] / 128;  // 50000 (packing requires <= 65536)
  const int E = in_sizes[1] / 2;    // 800000
  const int* src = edge_index;
  const int* dst = edge_index + E;

  const int B = (N + NPB - 1) >> SHIFT;     // 391 buckets
  const int nWG = (E + CHUNK - 1) / CHUNK;  // 196 blocks

  char* ws = (char*)d_ws;
  size_t off = 0;
  auto alloc = [&](size_t bytes) -> void* {
    void* p = ws + off;
    off += (bytes + 255) & ~(size_t)255;
    return p;
  };
  unsigned* keys = (unsigned*)alloc((size_t)E * 4);
  int* csr = (int*)alloc((size_t)E * 4);
  int* hist = (int*)alloc((size_t)B * nWG * 4);
  int* rowscan = (int*)alloc((size_t)B * nWG * 4);
  int* total = (int*)alloc((size_t)B * 4);
  int* base = (int*)alloc((size_t)(B + 1) * 4);
  int* eoff = (int*)alloc((size_t)N * 4);
  int* ecnt = (int*)alloc((size_t)N * 4);
  float* dinv = (float*)alloc((size_t)N * 4);
  float* h1s = (float*)alloc((size_t)N * 64 * 4);
  float* a1 = (float*)alloc((size_t)N * 64 * 4);
  float* h2s = h1s;  // alias: h1s dead after gather64

  hist_kernel<<<nWG, 256, 0, stream>>>(dst, E, nWG, B, hist);
  rowscan_kernel<<<B, 256, 0, stream>>>(hist, nWG, rowscan, total);
  basescan_kernel<<<1, 512, 0, stream>>>(total, B, base);
  scatterkeys_kernel<<<nWG, 256, 0, stream>>>(src, dst, E, nWG, B, rowscan, base, keys);
  bucket_build_kernel<<<B, 256, 0, stream>>>(keys, base, N, csr, eoff, ecnt, dinv);
  gemm1_kernel<<<(N + 63) / 64, 256, 0, stream>>>(x, W1, dinv, h1s, N);
  gather64_kernel<<<(N + 3) / 4, 256, 0, stream>>>(h1s, csr, eoff, ecnt, dinv, b1, a1, N);
  gemm2_kernel<<<(N + 127) / 128, 256, 0, stream>>>(a1, W2, dinv, h2s, N);
  gather32_kernel<<<(N + 7) / 8, 256, 0, stream>>>(h2s, csr, eoff, ecnt, dinv, b2, out, N);
}